// Round 1
// baseline (1219.353 us; speedup 1.0000x reference)
//
#include <hip/hip_runtime.h>
#include <math.h>

#define DT_F 0.1f

// scal[] slots
#define SC_Z     0
#define SC_RMEAN 1
#define SC_KMULT 2
#define SC_OP    3
#define SC_OPSTR 4
#define SC_SM    5

// ---------------------------------------------------------------- helpers

__device__ __forceinline__ float gelu_f(float x) {
    return 0.5f * x * (1.0f + erff(x * 0.7071067811865475f));
}

__device__ __forceinline__ unsigned rotl32(unsigned v, int d) {
    return (v << d) | (v >> (32 - d));
}

// JAX threefry2x32, 20 rounds
__device__ __forceinline__ void threefry2x32(unsigned k0, unsigned k1,
                                             unsigned x0, unsigned x1,
                                             unsigned& o0, unsigned& o1) {
    unsigned k2 = k0 ^ k1 ^ 0x1BD11BDAu;
    x0 += k0; x1 += k1;
    const int r0[4] = {13, 15, 26, 6};
    const int r1[4] = {17, 29, 16, 24};
#pragma unroll
    for (int g = 0; g < 5; ++g) {
        const int* R = (g & 1) ? r1 : r0;
#pragma unroll
        for (int q = 0; q < 4; ++q) { x0 += x1; x1 = rotl32(x1, R[q]); x1 ^= x0; }
        unsigned a, b;
        switch (g) {
            case 0:  a = k1; b = k2 + 1u; break;
            case 1:  a = k2; b = k0 + 2u; break;
            case 2:  a = k0; b = k1 + 3u; break;
            case 3:  a = k1; b = k2 + 4u; break;
            default: a = k2; b = k0 + 5u; break;
        }
        x0 += a; x1 += b;
    }
    o0 = x0; o1 = x1;
}

// XLA ErfInv32 (Giles polynomial)
__device__ __forceinline__ float erfinv_xla(float x) {
    float w = -log1pf(-x * x);
    float p;
    if (w < 5.0f) {
        w -= 2.5f;
        p = 2.81022636e-08f;
        p = fmaf(p, w, 3.43273939e-07f);
        p = fmaf(p, w, -3.5233877e-06f);
        p = fmaf(p, w, -4.39150654e-06f);
        p = fmaf(p, w, 0.00021858087f);
        p = fmaf(p, w, -0.00125372503f);
        p = fmaf(p, w, -0.00417768164f);
        p = fmaf(p, w, 0.246640727f);
        p = fmaf(p, w, 1.50140941f);
    } else {
        w = sqrtf(w) - 3.0f;
        p = -0.000200214257f;
        p = fmaf(p, w, 0.000100950558f);
        p = fmaf(p, w, 0.00134934322f);
        p = fmaf(p, w, -0.00367342844f);
        p = fmaf(p, w, 0.00573950773f);
        p = fmaf(p, w, -0.0076224613f);
        p = fmaf(p, w, 0.00943887047f);
        p = fmaf(p, w, 1.00167406f);
        p = fmaf(p, w, 2.83297682f);
    }
    return p * x;
}

// jax.random.normal(fold_in(key(42), li), (1024,256)) element at flat index
__device__ __forceinline__ float jax_normal_elem(unsigned fk0, unsigned fk1, unsigned flat) {
    const unsigned HALF = 131072u;  // 1024*256/2
    unsigned idx = (flat < HALF) ? flat : (flat - HALF);
    unsigned o0, o1;
    threefry2x32(fk0, fk1, idx, idx + HALF, o0, o1);
    unsigned bits = (flat < HALF) ? o0 : o1;
    float f = __uint_as_float((bits >> 9) | 0x3F800000u) - 1.0f;   // [0,1)
    const float LO = __uint_as_float(0xBF7FFFFFu);                  // -1 + 2^-24
    float u = fmaxf(LO, fmaf(f, 2.0f, LO));                         // maxval-minval == 2.0f exactly
    return 1.41421356237f * erfinv_xla(u);
}

// ---------------------------------------------------------------- init

__global__ __launch_bounds__(256) void init_kernel(float* scal, float* om_add) {
    int t = threadIdx.x;
    if (t < 8) {
        float v = 0.0f;
        if (t == SC_Z) v = 0.1f;
        if (t == SC_KMULT) v = 1.0f;
        scal[t] = v;
    }
    om_add[t] = 0.0f;
}

// ---------------------------------------------------------------- sinkhorn

__global__ __launch_bounds__(256) void sinkhorn_row(const float* __restrict__ src,
                                                    float* __restrict__ dst) {
    __shared__ float red[256];
    int i = blockIdx.x, j = threadIdx.x;
    float v = src[i * 256 + j];
    red[j] = v; __syncthreads();
#pragma unroll
    for (int off = 128; off > 0; off >>= 1) {
        if (j < off) red[j] = fmaxf(red[j], red[j + off]);
        __syncthreads();
    }
    float mx = red[0]; __syncthreads();
    red[j] = expf(v - mx); __syncthreads();
#pragma unroll
    for (int off = 128; off > 0; off >>= 1) {
        if (j < off) red[j] += red[j + off];
        __syncthreads();
    }
    float lse = mx + logf(red[0]);
    dst[i * 256 + j] = v - lse;
}

template <bool DO_EXP>
__global__ __launch_bounds__(256) void sinkhorn_col(float* __restrict__ P) {
    __shared__ float red[256];
    int c = blockIdx.x, t = threadIdx.x;
    float v = P[t * 256 + c];
    red[t] = v; __syncthreads();
#pragma unroll
    for (int off = 128; off > 0; off >>= 1) {
        if (t < off) red[t] = fmaxf(red[t], red[t + off]);
        __syncthreads();
    }
    float mx = red[0]; __syncthreads();
    red[t] = expf(v - mx); __syncthreads();
#pragma unroll
    for (int off = 128; off > 0; off >>= 1) {
        if (t < off) red[t] += red[t + off];
        __syncthreads();
    }
    float lse = mx + logf(red[0]);
    float r = v - lse;
    P[t * 256 + c] = DO_EXP ? expf(r) : r;
}

// ---------------------------------------------------------------- GEMM (f32, 64x64 tile)

// ACT: 0 none, 1 gelu, 2 tanh*pi
template <int ACT>
__global__ __launch_bounds__(256) void gemm_kernel(const float* __restrict__ A,
                                                   const float* __restrict__ W,
                                                   const float* __restrict__ bias,
                                                   float* __restrict__ C,
                                                   int M, int K, int N) {
    __shared__ float As[16][68];
    __shared__ float Bs[16][68];
    const int tid = threadIdx.x;
    const int tx = tid & 15;   // n dir
    const int ty = tid >> 4;   // m dir
    const int m_base = blockIdx.y * 64;
    const int n_base = blockIdx.x * 64;

    const int la_m = tid >> 2;         // 0..63
    const int la_k = (tid & 3) * 4;    // 0,4,8,12
    const int lb_k = tid >> 4;         // 0..15
    const int lb_n = (tid & 15) * 4;   // 0..60

    float acc[4][4] = {};

    for (int k0 = 0; k0 < K; k0 += 16) {
        float4 a4 = *reinterpret_cast<const float4*>(&A[(m_base + la_m) * K + k0 + la_k]);
        As[la_k + 0][la_m] = a4.x;
        As[la_k + 1][la_m] = a4.y;
        As[la_k + 2][la_m] = a4.z;
        As[la_k + 3][la_m] = a4.w;
        float4 b4 = *reinterpret_cast<const float4*>(&W[(k0 + lb_k) * N + n_base + lb_n]);
        *reinterpret_cast<float4*>(&Bs[lb_k][lb_n]) = b4;
        __syncthreads();
#pragma unroll
        for (int kk = 0; kk < 16; ++kk) {
            float4 ra = *reinterpret_cast<const float4*>(&As[kk][ty * 4]);
            float4 rb = *reinterpret_cast<const float4*>(&Bs[kk][tx * 4]);
            float raa[4] = {ra.x, ra.y, ra.z, ra.w};
            float rbb[4] = {rb.x, rb.y, rb.z, rb.w};
#pragma unroll
            for (int um = 0; um < 4; ++um)
#pragma unroll
                for (int un = 0; un < 4; ++un)
                    acc[um][un] = fmaf(raa[um], rbb[un], acc[um][un]);
        }
        __syncthreads();
    }

#pragma unroll
    for (int um = 0; um < 4; ++um) {
        int m = m_base + ty * 4 + um;
#pragma unroll
        for (int un = 0; un < 4; ++un) {
            int n = n_base + tx * 4 + un;
            float v = acc[um][un] + bias[n];
            if (ACT == 1) v = gelu_f(v);
            else if (ACT == 2) v = tanhf(v) * 3.14159274101257324f;
            C[m * N + n] = v;
        }
    }
}

// ---------------------------------------------------------------- Kuramoto layer (all 10 steps)

__global__ __launch_bounds__(256) void kuramoto_kernel(float* __restrict__ theta,
                                                       const float* __restrict__ Kl,
                                                       const float* __restrict__ omega_l,
                                                       const float* __restrict__ Kg_p,
                                                       const float* __restrict__ scal,
                                                       const float* __restrict__ om_add,
                                                       float* __restrict__ r_out) {
    __shared__ float s_s[4][256];
    __shared__ float s_c[4][256];
    const int i = threadIdx.x;
    const int b0 = blockIdx.x * 4;

    float th[4];
#pragma unroll
    for (int rr = 0; rr < 4; ++rr) th[rr] = theta[(b0 + rr) * 256 + i];

    const float om = omega_l[i] + om_add[i];
    const float gk = (*Kg_p) * (1.0f / 256.0f) * scal[SC_KMULT];

    for (int s = 0; s < 10; ++s) {
        float si[4], ci[4];
#pragma unroll
        for (int rr = 0; rr < 4; ++rr) {
            float sv, cv;
            sincosf(th[rr], &sv, &cv);
            si[rr] = sv; ci[rr] = cv;
            s_s[rr][i] = sv; s_c[rr][i] = cv;
        }
        __syncthreads();

        float A[4] = {0.f, 0.f, 0.f, 0.f};
        float B[4] = {0.f, 0.f, 0.f, 0.f};
#pragma unroll 2
        for (int j = 0; j < 256; j += 4) {
            float k0 = Kl[(j + 0) * 256 + i];
            float k1 = Kl[(j + 1) * 256 + i];
            float k2 = Kl[(j + 2) * 256 + i];
            float k3 = Kl[(j + 3) * 256 + i];
#pragma unroll
            for (int rr = 0; rr < 4; ++rr) {
                float4 s4 = *reinterpret_cast<const float4*>(&s_s[rr][j]);
                float4 c4 = *reinterpret_cast<const float4*>(&s_c[rr][j]);
                A[rr] = fmaf(k0, s4.x, A[rr]);
                A[rr] = fmaf(k1, s4.y, A[rr]);
                A[rr] = fmaf(k2, s4.z, A[rr]);
                A[rr] = fmaf(k3, s4.w, A[rr]);
                B[rr] = fmaf(k0, c4.x, B[rr]);
                B[rr] = fmaf(k1, c4.y, B[rr]);
                B[rr] = fmaf(k2, c4.z, B[rr]);
                B[rr] = fmaf(k3, c4.w, B[rr]);
            }
        }
        __syncthreads();

#pragma unroll
        for (int rr = 0; rr < 4; ++rr) {
            float coup = ci[rr] * A[rr] - si[rr] * B[rr];
            float t = th[rr] + DT_F * (om + gk * coup);
            float sv, cv;
            sincosf(t, &sv, &cv);
            th[rr] = atan2f(sv, cv);
        }
    }

    // order parameter r = |mean exp(i*theta)|
#pragma unroll
    for (int rr = 0; rr < 4; ++rr) {
        float sv, cv;
        sincosf(th[rr], &sv, &cv);
        s_s[rr][i] = sv; s_c[rr][i] = cv;
    }
    __syncthreads();
#pragma unroll
    for (int off = 128; off > 0; off >>= 1) {
        if (i < off) {
#pragma unroll
            for (int rr = 0; rr < 4; ++rr) {
                s_s[rr][i] += s_s[rr][i + off];
                s_c[rr][i] += s_c[rr][i + off];
            }
        }
        __syncthreads();
    }
    if (i < 4) {
        float cm = s_c[i][0] * (1.0f / 256.0f);
        float sm = s_s[i][0] * (1.0f / 256.0f);
        r_out[b0 + i] = sqrtf(cm * cm + sm * sm);
    }
#pragma unroll
    for (int rr = 0; rr < 4; ++rr) theta[(b0 + rr) * 256 + i] = th[rr];
}

// ---------------------------------------------------------------- z update (+ rmean)

__global__ __launch_bounds__(256) void z_update_kernel(const float* __restrict__ r,
                                                       float* __restrict__ scal,
                                                       const float* __restrict__ zm_p,
                                                       const float* __restrict__ zd_p) {
    __shared__ float red[256];
    int t = threadIdx.x;
    red[t] = r[t] + r[t + 256] + r[t + 512] + r[t + 768];
    __syncthreads();
#pragma unroll
    for (int off = 128; off > 0; off >>= 1) {
        if (t < off) red[t] += red[t + off];
        __syncthreads();
    }
    if (t == 0) {
        float rmean = red[0] * (1.0f / 1024.0f);
        float z = scal[SC_Z];
        float dz = (*zm_p) * (rmean - z) - (*zd_p) * (z - 0.5f);
        z = z + 0.01f * dz;
        z = fminf(fmaxf(z, 0.0f), 1.0f);
        scal[SC_Z] = z;
        scal[SC_RMEAN] = rmean;
    }
}

// ---------------------------------------------------------------- selection MLP (batched hidden mean)

__global__ __launch_bounds__(256) void sel_partial_kernel(const float* __restrict__ theta,
                                                          const float* __restrict__ r,
                                                          const float* __restrict__ scal,
                                                          const float* __restrict__ W1,
                                                          const float* __restrict__ b1,
                                                          float* __restrict__ partial) {
    __shared__ float red[4][64];
    const int h = threadIdx.x & 63;
    const int g = threadIdx.x >> 6;
    const int blk = blockIdx.x;
    const float z = scal[SC_Z];

    float acc = 0.0f;
    for (int b = blk * 64 + g; b < blk * 64 + 64; b += 4) {
        const float* th = theta + b * 256;
        float dot = b1[h];
#pragma unroll 4
        for (int k = 0; k < 256; ++k) dot = fmaf(th[k], W1[k * 64 + h], dot);
        dot = fmaf(r[b], W1[256 * 64 + h], dot);
        dot = fmaf(z, W1[257 * 64 + h], dot);
        acc += gelu_f(dot);
    }
    red[g][h] = acc;
    __syncthreads();
    if (g == 0) partial[blk * 64 + h] = red[0][h] + red[1][h] + red[2][h] + red[3][h];
}

__global__ __launch_bounds__(256) void op_finalize_kernel(const float* __restrict__ partial,
                                                          const float* __restrict__ W2,
                                                          const float* __restrict__ b2,
                                                          const float* __restrict__ opstr,
                                                          const float* __restrict__ cf,
                                                          float* __restrict__ scal,
                                                          float* __restrict__ om_add) {
    __shared__ float hbar[64];
    __shared__ float s_sm;
    __shared__ int s_op;
    const int t = threadIdx.x;
    if (t < 64) {
        float s = 0.0f;
#pragma unroll
        for (int blk = 0; blk < 16; ++blk) s += partial[blk * 64 + t];
        hbar[t] = s * (1.0f / 1024.0f);
    }
    __syncthreads();
    if (t == 0) {
        float best = -1e30f;
        int op = 0;
#pragma unroll
        for (int o = 0; o < 6; ++o) {
            float l = b2[o];
            for (int hh = 0; hh < 64; ++hh) l = fmaf(hbar[hh], W2[hh * 6 + o], l);
            if (l > best) { best = l; op = o; }
        }
        float sm = opstr[op] * scal[SC_RMEAN];
        scal[SC_OP] = (float)op;
        scal[SC_OPSTR] = opstr[op];
        scal[SC_SM] = sm;
        scal[SC_KMULT] = (op == 1) ? (1.0f + sm * 0.5f)
                        : (op == 2) ? (1.0f - sm * 0.3f) : 1.0f;
        s_sm = sm;
        s_op = op;
    }
    __syncthreads();
    om_add[t] = (s_op == 5) ? cf[t] * s_sm : 0.0f;
}

// ---------------------------------------------------------------- apply operator (EXCHANGE / INHIBIT)

__global__ __launch_bounds__(256) void apply_op_kernel(float* __restrict__ theta,
                                                       const float* __restrict__ P,
                                                       const float* __restrict__ r,
                                                       const float* __restrict__ scal,
                                                       int li) {
    __shared__ float th[8][256];
    const int op = (int)scal[SC_OP];
    const int i = threadIdx.x;
    const int b0 = blockIdx.x * 8;

    if (op == 3) {
#pragma unroll
        for (int rr = 0; rr < 8; ++rr) th[rr][i] = theta[(b0 + rr) * 256 + i];
        __syncthreads();
        float acc[8] = {0.f, 0.f, 0.f, 0.f, 0.f, 0.f, 0.f, 0.f};
        for (int j = 0; j < 256; ++j) {
            float pv = P[j * 256 + i];
#pragma unroll
            for (int rr = 0; rr < 8; ++rr) acc[rr] = fmaf(th[rr][j], pv, acc[rr]);
        }
#pragma unroll
        for (int rr = 0; rr < 8; ++rr) theta[(b0 + rr) * 256 + i] = acc[rr];
    } else if (op == 4) {
        unsigned fk0, fk1;
        threefry2x32(0u, 42u, 0u, (unsigned)li, fk0, fk1);
        const float opv = scal[SC_OPSTR];
#pragma unroll
        for (int rr = 0; rr < 8; ++rr) {
            int b = b0 + rr;
            unsigned flat = (unsigned)(b * 256 + i);
            float nz = jax_normal_elem(fk0, fk1, flat);
            float strength = opv * r[b];
            theta[b * 256 + i] += nz * strength * 0.2f;
        }
    }
}

// ---------------------------------------------------------------- phase embedding

__global__ __launch_bounds__(256) void emb_kernel(const float* __restrict__ theta,
                                                  float* __restrict__ emb) {
    int idx = blockIdx.x * 256 + threadIdx.x;   // over B*256
    int b = idx >> 8, i = idx & 255;
    float t = theta[idx];
    float sv, cv;
    sincosf(t, &sv, &cv);
    emb[b * 512 + i] = cv;
    emb[b * 512 + 256 + i] = sv;
}

// ---------------------------------------------------------------- launch

extern "C" void kernel_launch(void* const* d_in, const int* in_sizes, int n_in,
                              void* d_out, int out_size, void* d_ws, size_t ws_size,
                              hipStream_t stream) {
    const float* x     = (const float*)d_in[0];
    const float* eW1   = (const float*)d_in[1];
    const float* eb1   = (const float*)d_in[2];
    const float* eW2   = (const float*)d_in[3];
    const float* eb2   = (const float*)d_in[4];
    const float* K     = (const float*)d_in[5];
    const float* omega = (const float*)d_in[6];
    const float* Kg    = (const float*)d_in[7];
    const float* opstr = (const float*)d_in[8];
    const float* exlog = (const float*)d_in[9];
    const float* cfreq = (const float*)d_in[10];
    const float* sW1   = (const float*)d_in[11];
    const float* sb1   = (const float*)d_in[12];
    const float* sW2   = (const float*)d_in[13];
    const float* sb2   = (const float*)d_in[14];
    const float* dW1   = (const float*)d_in[15];
    const float* db1   = (const float*)d_in[16];
    const float* dW2   = (const float*)d_in[17];
    const float* db2   = (const float*)d_in[18];
    const float* zm    = (const float*)d_in[19];
    const float* zd    = (const float*)d_in[20];
    float* out = (float*)d_out;

    float* ws      = (float*)d_ws;
    float* P       = ws;               // 65536
    float* theta   = P + 65536;        // 262144
    float* h       = theta + 262144;   // 524288 (enc hidden, reused as emb)
    float* dh      = h + 524288;       // 262144 (dec hidden)
    float* rbuf    = dh + 262144;      // 1024
    float* scal    = rbuf + 1024;      // 8
    float* om_add  = scal + 8;         // 256
    float* partial = om_add + 256;     // 1024

    init_kernel<<<1, 256, 0, stream>>>(scal, om_add);

    // Sinkhorn: 5x (row-LSE, col-LSE), exp fused into last col pass
    sinkhorn_row<<<256, 256, 0, stream>>>(exlog, P);
    sinkhorn_col<false><<<256, 256, 0, stream>>>(P);
    for (int it = 1; it < 5; ++it) {
        sinkhorn_row<<<256, 256, 0, stream>>>(P, P);
        if (it < 4) sinkhorn_col<false><<<256, 256, 0, stream>>>(P);
        else        sinkhorn_col<true><<<256, 256, 0, stream>>>(P);
    }

    // encoder
    gemm_kernel<1><<<dim3(8, 16), 256, 0, stream>>>(x, eW1, eb1, h, 1024, 512, 512);
    gemm_kernel<2><<<dim3(4, 16), 256, 0, stream>>>(h, eW2, eb2, theta, 1024, 512, 256);

    // layers
    for (int li = 0; li < 4; ++li) {
        kuramoto_kernel<<<256, 256, 0, stream>>>(theta, K + li * 65536, omega + li * 256,
                                                 Kg + li, scal, om_add, rbuf);
        z_update_kernel<<<1, 256, 0, stream>>>(rbuf, scal, zm, zd);
        sel_partial_kernel<<<16, 256, 0, stream>>>(theta, rbuf, scal, sW1, sb1, partial);
        op_finalize_kernel<<<1, 256, 0, stream>>>(partial, sW2, sb2, opstr, cfreq, scal, om_add);
        apply_op_kernel<<<128, 256, 0, stream>>>(theta, P, rbuf, scal, li);
    }

    // decoder
    emb_kernel<<<1024, 256, 0, stream>>>(theta, h);
    gemm_kernel<1><<<dim3(4, 16), 256, 0, stream>>>(h, dW1, db1, dh, 1024, 512, 256);
    gemm_kernel<0><<<dim3(2, 16), 256, 0, stream>>>(dh, dW2, db2, out, 1024, 256, 128);

    (void)in_sizes; (void)n_in; (void)out_size; (void)ws_size;
}

// Round 2
// 691.421 us; speedup vs baseline: 1.7635x; 1.7635x over previous
//
#include <hip/hip_runtime.h>
#include <math.h>

#define DT_F 0.1f

// scal[] slots
#define SC_Z     0
#define SC_RMEAN 1
#define SC_KMULT 2
#define SC_OP    3
#define SC_OPSTR 4
#define SC_SM    5

// ---------------------------------------------------------------- helpers

__device__ __forceinline__ float gelu_f(float x) {
    return 0.5f * x * (1.0f + erff(x * 0.7071067811865475f));
}

__device__ __forceinline__ unsigned rotl32(unsigned v, int d) {
    return (v << d) | (v >> (32 - d));
}

// JAX threefry2x32, 20 rounds
__device__ __forceinline__ void threefry2x32(unsigned k0, unsigned k1,
                                             unsigned x0, unsigned x1,
                                             unsigned& o0, unsigned& o1) {
    unsigned k2 = k0 ^ k1 ^ 0x1BD11BDAu;
    x0 += k0; x1 += k1;
    const int r0[4] = {13, 15, 26, 6};
    const int r1[4] = {17, 29, 16, 24};
#pragma unroll
    for (int g = 0; g < 5; ++g) {
        const int* R = (g & 1) ? r1 : r0;
#pragma unroll
        for (int q = 0; q < 4; ++q) { x0 += x1; x1 = rotl32(x1, R[q]); x1 ^= x0; }
        unsigned a, b;
        switch (g) {
            case 0:  a = k1; b = k2 + 1u; break;
            case 1:  a = k2; b = k0 + 2u; break;
            case 2:  a = k0; b = k1 + 3u; break;
            case 3:  a = k1; b = k2 + 4u; break;
            default: a = k2; b = k0 + 5u; break;
        }
        x0 += a; x1 += b;
    }
    o0 = x0; o1 = x1;
}

// XLA ErfInv32 (Giles polynomial)
__device__ __forceinline__ float erfinv_xla(float x) {
    float w = -log1pf(-x * x);
    float p;
    if (w < 5.0f) {
        w -= 2.5f;
        p = 2.81022636e-08f;
        p = fmaf(p, w, 3.43273939e-07f);
        p = fmaf(p, w, -3.5233877e-06f);
        p = fmaf(p, w, -4.39150654e-06f);
        p = fmaf(p, w, 0.00021858087f);
        p = fmaf(p, w, -0.00125372503f);
        p = fmaf(p, w, -0.00417768164f);
        p = fmaf(p, w, 0.246640727f);
        p = fmaf(p, w, 1.50140941f);
    } else {
        w = sqrtf(w) - 3.0f;
        p = -0.000200214257f;
        p = fmaf(p, w, 0.000100950558f);
        p = fmaf(p, w, 0.00134934322f);
        p = fmaf(p, w, -0.00367342844f);
        p = fmaf(p, w, 0.00573950773f);
        p = fmaf(p, w, -0.0076224613f);
        p = fmaf(p, w, 0.00943887047f);
        p = fmaf(p, w, 1.00167406f);
        p = fmaf(p, w, 2.83297682f);
    }
    return p * x;
}

// jax.random.normal(fold_in(key(42), li), (1024,256)) element at flat index
__device__ __forceinline__ float jax_normal_elem(unsigned fk0, unsigned fk1, unsigned flat) {
    const unsigned HALF = 131072u;  // 1024*256/2
    unsigned idx = (flat < HALF) ? flat : (flat - HALF);
    unsigned o0, o1;
    threefry2x32(fk0, fk1, idx, idx + HALF, o0, o1);
    unsigned bits = (flat < HALF) ? o0 : o1;
    float f = __uint_as_float((bits >> 9) | 0x3F800000u) - 1.0f;   // [0,1)
    const float LO = __uint_as_float(0xBF7FFFFFu);                  // -1 + 2^-24
    float u = fmaxf(LO, fmaf(f, 2.0f, LO));                         // maxval-minval == 2.0f exactly
    return 1.41421356237f * erfinv_xla(u);
}

// ---------------------------------------------------------------- init

__global__ __launch_bounds__(256) void init_kernel(float* scal, float* om_add) {
    int t = threadIdx.x;
    if (t < 8) {
        float v = 0.0f;
        if (t == SC_Z) v = 0.1f;
        if (t == SC_KMULT) v = 1.0f;
        scal[t] = v;
    }
    om_add[t] = 0.0f;
}

// ---------------------------------------------------------------- sinkhorn

__global__ __launch_bounds__(256) void sinkhorn_row(const float* __restrict__ src,
                                                    float* __restrict__ dst) {
    __shared__ float red[256];
    int i = blockIdx.x, j = threadIdx.x;
    float v = src[i * 256 + j];
    red[j] = v; __syncthreads();
#pragma unroll
    for (int off = 128; off > 0; off >>= 1) {
        if (j < off) red[j] = fmaxf(red[j], red[j + off]);
        __syncthreads();
    }
    float mx = red[0]; __syncthreads();
    red[j] = expf(v - mx); __syncthreads();
#pragma unroll
    for (int off = 128; off > 0; off >>= 1) {
        if (j < off) red[j] += red[j + off];
        __syncthreads();
    }
    float lse = mx + logf(red[0]);
    dst[i * 256 + j] = v - lse;
}

template <bool DO_EXP>
__global__ __launch_bounds__(256) void sinkhorn_col(float* __restrict__ P) {
    __shared__ float red[256];
    int c = blockIdx.x, t = threadIdx.x;
    float v = P[t * 256 + c];
    red[t] = v; __syncthreads();
#pragma unroll
    for (int off = 128; off > 0; off >>= 1) {
        if (t < off) red[t] = fmaxf(red[t], red[t + off]);
        __syncthreads();
    }
    float mx = red[0]; __syncthreads();
    red[t] = expf(v - mx); __syncthreads();
#pragma unroll
    for (int off = 128; off > 0; off >>= 1) {
        if (t < off) red[t] += red[t + off];
        __syncthreads();
    }
    float lse = mx + logf(red[0]);
    float r = v - lse;
    P[t * 256 + c] = DO_EXP ? expf(r) : r;
}

// ---------------------------------------------------------------- GEMM (f32, 64x64 tile)

// ACT: 0 none, 1 gelu, 2 tanh*pi
template <int ACT>
__global__ __launch_bounds__(256) void gemm_kernel(const float* __restrict__ A,
                                                   const float* __restrict__ W,
                                                   const float* __restrict__ bias,
                                                   float* __restrict__ C,
                                                   int M, int K, int N) {
    __shared__ float As[16][68];
    __shared__ float Bs[16][68];
    const int tid = threadIdx.x;
    const int tx = tid & 15;   // n dir
    const int ty = tid >> 4;   // m dir
    const int m_base = blockIdx.y * 64;
    const int n_base = blockIdx.x * 64;

    const int la_m = tid >> 2;         // 0..63
    const int la_k = (tid & 3) * 4;    // 0,4,8,12
    const int lb_k = tid >> 4;         // 0..15
    const int lb_n = (tid & 15) * 4;   // 0..60

    float acc[4][4] = {};

    for (int k0 = 0; k0 < K; k0 += 16) {
        float4 a4 = *reinterpret_cast<const float4*>(&A[(m_base + la_m) * K + k0 + la_k]);
        As[la_k + 0][la_m] = a4.x;
        As[la_k + 1][la_m] = a4.y;
        As[la_k + 2][la_m] = a4.z;
        As[la_k + 3][la_m] = a4.w;
        float4 b4 = *reinterpret_cast<const float4*>(&W[(k0 + lb_k) * N + n_base + lb_n]);
        *reinterpret_cast<float4*>(&Bs[lb_k][lb_n]) = b4;
        __syncthreads();
#pragma unroll
        for (int kk = 0; kk < 16; ++kk) {
            float4 ra = *reinterpret_cast<const float4*>(&As[kk][ty * 4]);
            float4 rb = *reinterpret_cast<const float4*>(&Bs[kk][tx * 4]);
            float raa[4] = {ra.x, ra.y, ra.z, ra.w};
            float rbb[4] = {rb.x, rb.y, rb.z, rb.w};
#pragma unroll
            for (int um = 0; um < 4; ++um)
#pragma unroll
                for (int un = 0; un < 4; ++un)
                    acc[um][un] = fmaf(raa[um], rbb[un], acc[um][un]);
        }
        __syncthreads();
    }

#pragma unroll
    for (int um = 0; um < 4; ++um) {
        int m = m_base + ty * 4 + um;
#pragma unroll
        for (int un = 0; un < 4; ++un) {
            int n = n_base + tx * 4 + un;
            float v = acc[um][un] + bias[n];
            if (ACT == 1) v = gelu_f(v);
            else if (ACT == 2) v = tanhf(v) * 3.14159274101257324f;
            C[m * N + n] = v;
        }
    }
}

// ---------------------------------------------------------------- Kuramoto layer (all 10 steps)

__global__ __launch_bounds__(256) void kuramoto_kernel(float* __restrict__ theta,
                                                       const float* __restrict__ Kl,
                                                       const float* __restrict__ omega_l,
                                                       const float* __restrict__ Kg_p,
                                                       const float* __restrict__ scal,
                                                       const float* __restrict__ om_add,
                                                       float* __restrict__ r_out) {
    __shared__ float s_s[4][256];
    __shared__ float s_c[4][256];
    const int i = threadIdx.x;
    const int b0 = blockIdx.x * 4;

    float th[4];
#pragma unroll
    for (int rr = 0; rr < 4; ++rr) th[rr] = theta[(b0 + rr) * 256 + i];

    const float om = omega_l[i] + om_add[i];
    const float gk = (*Kg_p) * (1.0f / 256.0f) * scal[SC_KMULT];

    for (int s = 0; s < 10; ++s) {
        float si[4], ci[4];
#pragma unroll
        for (int rr = 0; rr < 4; ++rr) {
            float sv, cv;
            sincosf(th[rr], &sv, &cv);
            si[rr] = sv; ci[rr] = cv;
            s_s[rr][i] = sv; s_c[rr][i] = cv;
        }
        __syncthreads();

        float A[4] = {0.f, 0.f, 0.f, 0.f};
        float B[4] = {0.f, 0.f, 0.f, 0.f};
#pragma unroll 2
        for (int j = 0; j < 256; j += 4) {
            float k0 = Kl[(j + 0) * 256 + i];
            float k1 = Kl[(j + 1) * 256 + i];
            float k2 = Kl[(j + 2) * 256 + i];
            float k3 = Kl[(j + 3) * 256 + i];
#pragma unroll
            for (int rr = 0; rr < 4; ++rr) {
                float4 s4 = *reinterpret_cast<const float4*>(&s_s[rr][j]);
                float4 c4 = *reinterpret_cast<const float4*>(&s_c[rr][j]);
                A[rr] = fmaf(k0, s4.x, A[rr]);
                A[rr] = fmaf(k1, s4.y, A[rr]);
                A[rr] = fmaf(k2, s4.z, A[rr]);
                A[rr] = fmaf(k3, s4.w, A[rr]);
                B[rr] = fmaf(k0, c4.x, B[rr]);
                B[rr] = fmaf(k1, c4.y, B[rr]);
                B[rr] = fmaf(k2, c4.z, B[rr]);
                B[rr] = fmaf(k3, c4.w, B[rr]);
            }
        }
        __syncthreads();

#pragma unroll
        for (int rr = 0; rr < 4; ++rr) {
            float coup = ci[rr] * A[rr] - si[rr] * B[rr];
            float t = th[rr] + DT_F * (om + gk * coup);
            float sv, cv;
            sincosf(t, &sv, &cv);
            th[rr] = atan2f(sv, cv);
        }
    }

    // order parameter r = |mean exp(i*theta)|
#pragma unroll
    for (int rr = 0; rr < 4; ++rr) {
        float sv, cv;
        sincosf(th[rr], &sv, &cv);
        s_s[rr][i] = sv; s_c[rr][i] = cv;
    }
    __syncthreads();
#pragma unroll
    for (int off = 128; off > 0; off >>= 1) {
        if (i < off) {
#pragma unroll
            for (int rr = 0; rr < 4; ++rr) {
                s_s[rr][i] += s_s[rr][i + off];
                s_c[rr][i] += s_c[rr][i + off];
            }
        }
        __syncthreads();
    }
    if (i < 4) {
        float cm = s_c[i][0] * (1.0f / 256.0f);
        float sm = s_s[i][0] * (1.0f / 256.0f);
        r_out[b0 + i] = sqrtf(cm * cm + sm * sm);
    }
#pragma unroll
    for (int rr = 0; rr < 4; ++rr) theta[(b0 + rr) * 256 + i] = th[rr];
}

// ---------------------------------------------------------------- z update (+ rmean)

__global__ __launch_bounds__(256) void z_update_kernel(const float* __restrict__ r,
                                                       float* __restrict__ scal,
                                                       const float* __restrict__ zm_p,
                                                       const float* __restrict__ zd_p) {
    __shared__ float red[256];
    int t = threadIdx.x;
    red[t] = r[t] + r[t + 256] + r[t + 512] + r[t + 768];
    __syncthreads();
#pragma unroll
    for (int off = 128; off > 0; off >>= 1) {
        if (t < off) red[t] += red[t + off];
        __syncthreads();
    }
    if (t == 0) {
        float rmean = red[0] * (1.0f / 1024.0f);
        float z = scal[SC_Z];
        float dz = (*zm_p) * (rmean - z) - (*zd_p) * (z - 0.5f);
        z = z + 0.01f * dz;
        z = fminf(fmaxf(z, 0.0f), 1.0f);
        scal[SC_Z] = z;
        scal[SC_RMEAN] = rmean;
    }
}

// ---------------------------------------------------------------- selection MLP (batched hidden mean)
// 256 blocks x 4 rows; each 256-dot split across 4 thread-groups of 64.

__global__ __launch_bounds__(256) void sel_partial_kernel(const float* __restrict__ theta,
                                                          const float* __restrict__ r,
                                                          const float* __restrict__ scal,
                                                          const float* __restrict__ W1,
                                                          const float* __restrict__ b1,
                                                          float* __restrict__ partial) {
    __shared__ float red[4][64];
    const int h = threadIdx.x & 63;
    const int part = threadIdx.x >> 6;   // 0..3 -> k-range [part*64, part*64+64)
    const int blk = blockIdx.x;
    const float z = scal[SC_Z];

    const float* wbase = W1 + part * 64 * 64 + h;
    float acc = 0.0f;

#pragma unroll
    for (int rr = 0; rr < 4; ++rr) {
        const int b = blk * 4 + rr;
        const float* th = theta + b * 256 + part * 64;
        float d0 = 0.f, d1 = 0.f, d2 = 0.f, d3 = 0.f;
#pragma unroll
        for (int kk = 0; kk < 64; kk += 4) {
            d0 = fmaf(th[kk + 0], wbase[(kk + 0) * 64], d0);
            d1 = fmaf(th[kk + 1], wbase[(kk + 1) * 64], d1);
            d2 = fmaf(th[kk + 2], wbase[(kk + 2) * 64], d2);
            d3 = fmaf(th[kk + 3], wbase[(kk + 3) * 64], d3);
        }
        red[part][h] = (d0 + d1) + (d2 + d3);
        __syncthreads();
        if (part == 0) {
            float full = red[0][h] + red[1][h] + red[2][h] + red[3][h] + b1[h]
                       + r[b] * W1[256 * 64 + h] + z * W1[257 * 64 + h];
            acc += gelu_f(full);
        }
        __syncthreads();
    }
    if (part == 0) partial[blk * 64 + h] = acc;
}

__global__ __launch_bounds__(256) void op_finalize_kernel(const float* __restrict__ partial,
                                                          const float* __restrict__ W2,
                                                          const float* __restrict__ b2,
                                                          const float* __restrict__ opstr,
                                                          const float* __restrict__ cf,
                                                          float* __restrict__ scal,
                                                          float* __restrict__ om_add) {
    __shared__ float red[4][64];
    __shared__ float hbar[64];
    __shared__ float s_sm;
    __shared__ int s_op;
    const int t = threadIdx.x;
    const int h = t & 63;
    const int q = t >> 6;   // 0..3 -> block-range [q*64, q*64+64)

    float s = 0.0f;
#pragma unroll 8
    for (int blk = q * 64; blk < q * 64 + 64; ++blk) s += partial[blk * 64 + h];
    red[q][h] = s;
    __syncthreads();
    if (t < 64) hbar[t] = (red[0][t] + red[1][t] + red[2][t] + red[3][t]) * (1.0f / 1024.0f);
    __syncthreads();
    if (t == 0) {
        float best = -1e30f;
        int op = 0;
#pragma unroll
        for (int o = 0; o < 6; ++o) {
            float l = b2[o];
            for (int hh = 0; hh < 64; ++hh) l = fmaf(hbar[hh], W2[hh * 6 + o], l);
            if (l > best) { best = l; op = o; }
        }
        float sm = opstr[op] * scal[SC_RMEAN];
        scal[SC_OP] = (float)op;
        scal[SC_OPSTR] = opstr[op];
        scal[SC_SM] = sm;
        scal[SC_KMULT] = (op == 1) ? (1.0f + sm * 0.5f)
                        : (op == 2) ? (1.0f - sm * 0.3f) : 1.0f;
        s_sm = sm;
        s_op = op;
    }
    __syncthreads();
    om_add[t] = (s_op == 5) ? cf[t] * s_sm : 0.0f;
}

// ---------------------------------------------------------------- apply operator (EXCHANGE / INHIBIT)

__global__ __launch_bounds__(256) void apply_op_kernel(float* __restrict__ theta,
                                                       const float* __restrict__ P,
                                                       const float* __restrict__ r,
                                                       const float* __restrict__ scal,
                                                       int li) {
    __shared__ float th[8][256];
    const int op = (int)scal[SC_OP];
    const int i = threadIdx.x;
    const int b0 = blockIdx.x * 8;

    if (op == 3) {
#pragma unroll
        for (int rr = 0; rr < 8; ++rr) th[rr][i] = theta[(b0 + rr) * 256 + i];
        __syncthreads();
        float acc[8] = {0.f, 0.f, 0.f, 0.f, 0.f, 0.f, 0.f, 0.f};
        for (int j = 0; j < 256; ++j) {
            float pv = P[j * 256 + i];
#pragma unroll
            for (int rr = 0; rr < 8; ++rr) acc[rr] = fmaf(th[rr][j], pv, acc[rr]);
        }
#pragma unroll
        for (int rr = 0; rr < 8; ++rr) theta[(b0 + rr) * 256 + i] = acc[rr];
    } else if (op == 4) {
        unsigned fk0, fk1;
        threefry2x32(0u, 42u, 0u, (unsigned)li, fk0, fk1);
        const float opv = scal[SC_OPSTR];
#pragma unroll
        for (int rr = 0; rr < 8; ++rr) {
            int b = b0 + rr;
            unsigned flat = (unsigned)(b * 256 + i);
            float nz = jax_normal_elem(fk0, fk1, flat);
            float strength = opv * r[b];
            theta[b * 256 + i] += nz * strength * 0.2f;
        }
    }
}

// ---------------------------------------------------------------- phase embedding

__global__ __launch_bounds__(256) void emb_kernel(const float* __restrict__ theta,
                                                  float* __restrict__ emb) {
    int idx = blockIdx.x * 256 + threadIdx.x;   // over B*256
    int b = idx >> 8, i = idx & 255;
    float t = theta[idx];
    float sv, cv;
    sincosf(t, &sv, &cv);
    emb[b * 512 + i] = cv;
    emb[b * 512 + 256 + i] = sv;
}

// ---------------------------------------------------------------- launch

extern "C" void kernel_launch(void* const* d_in, const int* in_sizes, int n_in,
                              void* d_out, int out_size, void* d_ws, size_t ws_size,
                              hipStream_t stream) {
    const float* x     = (const float*)d_in[0];
    const float* eW1   = (const float*)d_in[1];
    const float* eb1   = (const float*)d_in[2];
    const float* eW2   = (const float*)d_in[3];
    const float* eb2   = (const float*)d_in[4];
    const float* K     = (const float*)d_in[5];
    const float* omega = (const float*)d_in[6];
    const float* Kg    = (const float*)d_in[7];
    const float* opstr = (const float*)d_in[8];
    const float* exlog = (const float*)d_in[9];
    const float* cfreq = (const float*)d_in[10];
    const float* sW1   = (const float*)d_in[11];
    const float* sb1   = (const float*)d_in[12];
    const float* sW2   = (const float*)d_in[13];
    const float* sb2   = (const float*)d_in[14];
    const float* dW1   = (const float*)d_in[15];
    const float* db1   = (const float*)d_in[16];
    const float* dW2   = (const float*)d_in[17];
    const float* db2   = (const float*)d_in[18];
    const float* zm    = (const float*)d_in[19];
    const float* zd    = (const float*)d_in[20];
    float* out = (float*)d_out;

    float* ws      = (float*)d_ws;
    float* P       = ws;               // 65536
    float* theta   = P + 65536;        // 262144
    float* h       = theta + 262144;   // 524288 (enc hidden, reused as emb)
    float* dh      = h + 524288;       // 262144 (dec hidden)
    float* rbuf    = dh + 262144;      // 1024
    float* scal    = rbuf + 1024;      // 8
    float* om_add  = scal + 8;         // 256
    float* partial = om_add + 256;     // 256*64

    init_kernel<<<1, 256, 0, stream>>>(scal, om_add);

    // Sinkhorn: 5x (row-LSE, col-LSE), exp fused into last col pass
    sinkhorn_row<<<256, 256, 0, stream>>>(exlog, P);
    sinkhorn_col<false><<<256, 256, 0, stream>>>(P);
    for (int it = 1; it < 5; ++it) {
        sinkhorn_row<<<256, 256, 0, stream>>>(P, P);
        if (it < 4) sinkhorn_col<false><<<256, 256, 0, stream>>>(P);
        else        sinkhorn_col<true><<<256, 256, 0, stream>>>(P);
    }

    // encoder
    gemm_kernel<1><<<dim3(8, 16), 256, 0, stream>>>(x, eW1, eb1, h, 1024, 512, 512);
    gemm_kernel<2><<<dim3(4, 16), 256, 0, stream>>>(h, eW2, eb2, theta, 1024, 512, 256);

    // layers
    for (int li = 0; li < 4; ++li) {
        kuramoto_kernel<<<256, 256, 0, stream>>>(theta, K + li * 65536, omega + li * 256,
                                                 Kg + li, scal, om_add, rbuf);
        z_update_kernel<<<1, 256, 0, stream>>>(rbuf, scal, zm, zd);
        sel_partial_kernel<<<256, 256, 0, stream>>>(theta, rbuf, scal, sW1, sb1, partial);
        op_finalize_kernel<<<1, 256, 0, stream>>>(partial, sW2, sb2, opstr, cfreq, scal, om_add);
        apply_op_kernel<<<128, 256, 0, stream>>>(theta, P, rbuf, scal, li);
    }

    // decoder
    emb_kernel<<<1024, 256, 0, stream>>>(theta, h);
    gemm_kernel<1><<<dim3(4, 16), 256, 0, stream>>>(h, dW1, db1, dh, 1024, 512, 256);
    gemm_kernel<0><<<dim3(2, 16), 256, 0, stream>>>(dh, dW2, db2, out, 1024, 256, 128);

    (void)in_sizes; (void)n_in; (void)out_size; (void)ws_size;
}

// Round 3
// 335.019 us; speedup vs baseline: 3.6397x; 2.0638x over previous
//
#include <hip/hip_runtime.h>
#include <math.h>

#define DT_F 0.1f

// scal[] slots
#define SC_Z     0
#define SC_RMEAN 1
#define SC_KMULT 2
#define SC_OP    3
#define SC_OPSTR 4
#define SC_SM    5

typedef __attribute__((ext_vector_type(8))) short short8;
typedef __attribute__((ext_vector_type(4))) float f32x4;

// ---------------------------------------------------------------- helpers

__device__ __forceinline__ float gelu_f(float x) {
    return 0.5f * x * (1.0f + erff(x * 0.7071067811865475f));
}

__device__ __forceinline__ unsigned short f2bf_rne(float f) {
    union { float f; unsigned u; } v; v.f = f;
    unsigned x = v.u;
    unsigned r = x + 0x7fffu + ((x >> 16) & 1u);
    return (unsigned short)(r >> 16);
}

__device__ __forceinline__ unsigned rotl32(unsigned v, int d) {
    return (v << d) | (v >> (32 - d));
}

// JAX threefry2x32, 20 rounds
__device__ __forceinline__ void threefry2x32(unsigned k0, unsigned k1,
                                             unsigned x0, unsigned x1,
                                             unsigned& o0, unsigned& o1) {
    unsigned k2 = k0 ^ k1 ^ 0x1BD11BDAu;
    x0 += k0; x1 += k1;
    const int r0[4] = {13, 15, 26, 6};
    const int r1[4] = {17, 29, 16, 24};
#pragma unroll
    for (int g = 0; g < 5; ++g) {
        const int* R = (g & 1) ? r1 : r0;
#pragma unroll
        for (int q = 0; q < 4; ++q) { x0 += x1; x1 = rotl32(x1, R[q]); x1 ^= x0; }
        unsigned a, b;
        switch (g) {
            case 0:  a = k1; b = k2 + 1u; break;
            case 1:  a = k2; b = k0 + 2u; break;
            case 2:  a = k0; b = k1 + 3u; break;
            case 3:  a = k1; b = k2 + 4u; break;
            default: a = k2; b = k0 + 5u; break;
        }
        x0 += a; x1 += b;
    }
    o0 = x0; o1 = x1;
}

// XLA ErfInv32 (Giles polynomial)
__device__ __forceinline__ float erfinv_xla(float x) {
    float w = -log1pf(-x * x);
    float p;
    if (w < 5.0f) {
        w -= 2.5f;
        p = 2.81022636e-08f;
        p = fmaf(p, w, 3.43273939e-07f);
        p = fmaf(p, w, -3.5233877e-06f);
        p = fmaf(p, w, -4.39150654e-06f);
        p = fmaf(p, w, 0.00021858087f);
        p = fmaf(p, w, -0.00125372503f);
        p = fmaf(p, w, -0.00417768164f);
        p = fmaf(p, w, 0.246640727f);
        p = fmaf(p, w, 1.50140941f);
    } else {
        w = sqrtf(w) - 3.0f;
        p = -0.000200214257f;
        p = fmaf(p, w, 0.000100950558f);
        p = fmaf(p, w, 0.00134934322f);
        p = fmaf(p, w, -0.00367342844f);
        p = fmaf(p, w, 0.00573950773f);
        p = fmaf(p, w, -0.0076224613f);
        p = fmaf(p, w, 0.00943887047f);
        p = fmaf(p, w, 1.00167406f);
        p = fmaf(p, w, 2.83297682f);
    }
    return p * x;
}

// jax.random.normal(fold_in(key(42), li), (1024,256)) element at flat index
__device__ __forceinline__ float jax_normal_elem(unsigned fk0, unsigned fk1, unsigned flat) {
    const unsigned HALF = 131072u;  // 1024*256/2
    unsigned idx = (flat < HALF) ? flat : (flat - HALF);
    unsigned o0, o1;
    threefry2x32(fk0, fk1, idx, idx + HALF, o0, o1);
    unsigned bits = (flat < HALF) ? o0 : o1;
    float f = __uint_as_float((bits >> 9) | 0x3F800000u) - 1.0f;   // [0,1)
    const float LO = __uint_as_float(0xBF7FFFFFu);                  // -1 + 2^-24
    float u = fmaxf(LO, fmaf(f, 2.0f, LO));                         // maxval-minval == 2.0f exactly
    return 1.41421356237f * erfinv_xla(u);
}

// ---------------------------------------------------------------- init

__global__ __launch_bounds__(256) void init_kernel(float* scal, float* om_add) {
    int t = threadIdx.x;
    if (t < 8) {
        float v = 0.0f;
        if (t == SC_Z) v = 0.1f;
        if (t == SC_KMULT) v = 1.0f;
        scal[t] = v;
    }
    om_add[t] = 0.0f;
}

// ---------------------------------------------------------------- sinkhorn

__global__ __launch_bounds__(256) void sinkhorn_row(const float* __restrict__ src,
                                                    float* __restrict__ dst) {
    __shared__ float red[256];
    int i = blockIdx.x, j = threadIdx.x;
    float v = src[i * 256 + j];
    red[j] = v; __syncthreads();
#pragma unroll
    for (int off = 128; off > 0; off >>= 1) {
        if (j < off) red[j] = fmaxf(red[j], red[j + off]);
        __syncthreads();
    }
    float mx = red[0]; __syncthreads();
    red[j] = expf(v - mx); __syncthreads();
#pragma unroll
    for (int off = 128; off > 0; off >>= 1) {
        if (j < off) red[j] += red[j + off];
        __syncthreads();
    }
    float lse = mx + logf(red[0]);
    dst[i * 256 + j] = v - lse;
}

template <bool DO_EXP>
__global__ __launch_bounds__(256) void sinkhorn_col(float* __restrict__ P) {
    __shared__ float red[256];
    int c = blockIdx.x, t = threadIdx.x;
    float v = P[t * 256 + c];
    red[t] = v; __syncthreads();
#pragma unroll
    for (int off = 128; off > 0; off >>= 1) {
        if (t < off) red[t] = fmaxf(red[t], red[t + off]);
        __syncthreads();
    }
    float mx = red[0]; __syncthreads();
    red[t] = expf(v - mx); __syncthreads();
#pragma unroll
    for (int off = 128; off > 0; off >>= 1) {
        if (t < off) red[t] += red[t + off];
        __syncthreads();
    }
    float lse = mx + logf(red[0]);
    float r = v - lse;
    P[t * 256 + c] = DO_EXP ? expf(r) : r;
}

// ---------------------------------------------------------------- GEMM (f32, 64x64 tile)

// ACT: 0 none, 1 gelu, 2 tanh*pi
template <int ACT>
__global__ __launch_bounds__(256) void gemm_kernel(const float* __restrict__ A,
                                                   const float* __restrict__ W,
                                                   const float* __restrict__ bias,
                                                   float* __restrict__ C,
                                                   int M, int K, int N) {
    __shared__ float As[16][68];
    __shared__ float Bs[16][68];
    const int tid = threadIdx.x;
    const int tx = tid & 15;   // n dir
    const int ty = tid >> 4;   // m dir
    const int m_base = blockIdx.y * 64;
    const int n_base = blockIdx.x * 64;

    const int la_m = tid >> 2;         // 0..63
    const int la_k = (tid & 3) * 4;    // 0,4,8,12
    const int lb_k = tid >> 4;         // 0..15
    const int lb_n = (tid & 15) * 4;   // 0..60

    float acc[4][4] = {};

    for (int k0 = 0; k0 < K; k0 += 16) {
        float4 a4 = *reinterpret_cast<const float4*>(&A[(m_base + la_m) * K + k0 + la_k]);
        As[la_k + 0][la_m] = a4.x;
        As[la_k + 1][la_m] = a4.y;
        As[la_k + 2][la_m] = a4.z;
        As[la_k + 3][la_m] = a4.w;
        float4 b4 = *reinterpret_cast<const float4*>(&W[(k0 + lb_k) * N + n_base + lb_n]);
        *reinterpret_cast<float4*>(&Bs[lb_k][lb_n]) = b4;
        __syncthreads();
#pragma unroll
        for (int kk = 0; kk < 16; ++kk) {
            float4 ra = *reinterpret_cast<const float4*>(&As[kk][ty * 4]);
            float4 rb = *reinterpret_cast<const float4*>(&Bs[kk][tx * 4]);
            float raa[4] = {ra.x, ra.y, ra.z, ra.w};
            float rbb[4] = {rb.x, rb.y, rb.z, rb.w};
#pragma unroll
            for (int um = 0; um < 4; ++um)
#pragma unroll
                for (int un = 0; un < 4; ++un)
                    acc[um][un] = fmaf(raa[um], rbb[un], acc[um][un]);
        }
        __syncthreads();
    }

#pragma unroll
    for (int um = 0; um < 4; ++um) {
        int m = m_base + ty * 4 + um;
#pragma unroll
        for (int un = 0; un < 4; ++un) {
            int n = n_base + tx * 4 + un;
            float v = acc[um][un] + bias[n];
            if (ACT == 1) v = gelu_f(v);
            else if (ACT == 2) v = tanhf(v) * 3.14159274101257324f;
            C[m * N + n] = v;
        }
    }
}

// ---------------------------------------------------------------- Kuramoto layer via MFMA
// 64 blocks x 512 threads (8 waves). Block owns 16 batch rows for all 10 steps.
// Wave w owns output cols [w*32, w*32+32). K fragments live in registers (bf16),
// loaded ONCE per layer. theta persists in MFMA C/D layout:
//   col = lane&15 (+nf*16+cb), row = (lane>>4)*4 + q.
// sin/cos staged per step to LDS (bf16) for A-fragments:
//   A: row = lane&15, k = (lane>>4)*8 + u  (b128 read).

__global__ __launch_bounds__(512) void kuramoto_mfma_kernel(
    float* __restrict__ theta,
    const float* __restrict__ Kl,
    const float* __restrict__ omega_l,
    const float* __restrict__ Kg_p,
    const float* __restrict__ scal,
    const float* __restrict__ om_add,
    float* __restrict__ r_out)
{
    __shared__ __align__(16) unsigned short s_lds[16][264];
    __shared__ __align__(16) unsigned short c_lds[16][264];
    __shared__ float rp_s[16][128];
    __shared__ float rp_c[16][128];
    __shared__ float red_s[16][32];
    __shared__ float red_c[16][32];

    const int tid = threadIdx.x;
    const int l  = tid & 63;
    const int w  = tid >> 6;     // wave 0..7
    const int lo = l & 15;
    const int hi = l >> 4;       // 0..3
    const int cb = w * 32;
    const int r0 = blockIdx.x * 16;

    const float gk = Kg_p[0] * (1.0f / 256.0f) * scal[SC_KMULT];

    // ---- K fragments (registers, bf16), once per layer -----------------
    short8 kfrag[8][2];
#pragma unroll
    for (int ks = 0; ks < 8; ++ks) {
#pragma unroll
        for (int nf = 0; nf < 2; ++nf) {
            const int col = cb + nf * 16 + lo;
            const int kb = ks * 32 + hi * 8;
            short8 f;
#pragma unroll
            for (int u = 0; u < 8; ++u)
                f[u] = (short)f2bf_rne(Kl[(kb + u) * 256 + col]);
            kfrag[ks][nf] = f;
        }
    }

    // ---- initial theta load + sincos staging ---------------------------
    float t[2][4], si[2][4], ci[2][4];
    float om[2];
#pragma unroll
    for (int nf = 0; nf < 2; ++nf) {
        const int col = cb + nf * 16 + lo;
        om[nf] = omega_l[col] + om_add[col];
#pragma unroll
        for (int q = 0; q < 4; ++q) {
            const int row = hi * 4 + q;
            float th = theta[(r0 + row) * 256 + col];
            t[nf][q] = th;
            float sv, cv;
            sincosf(th, &sv, &cv);
            si[nf][q] = sv; ci[nf][q] = cv;
            s_lds[row][col] = f2bf_rne(sv);
            c_lds[row][col] = f2bf_rne(cv);
        }
    }
    __syncthreads();

    // ---- 10 steps -------------------------------------------------------
    for (int s = 0; s < 10; ++s) {
        f32x4 accS0 = {0.f, 0.f, 0.f, 0.f};
        f32x4 accS1 = {0.f, 0.f, 0.f, 0.f};
        f32x4 accC0 = {0.f, 0.f, 0.f, 0.f};
        f32x4 accC1 = {0.f, 0.f, 0.f, 0.f};
#pragma unroll
        for (int ks = 0; ks < 8; ++ks) {
            short8 aS = *reinterpret_cast<const short8*>(&s_lds[lo][ks * 32 + hi * 8]);
            short8 aC = *reinterpret_cast<const short8*>(&c_lds[lo][ks * 32 + hi * 8]);
            accS0 = __builtin_amdgcn_mfma_f32_16x16x32_bf16(aS, kfrag[ks][0], accS0, 0, 0, 0);
            accS1 = __builtin_amdgcn_mfma_f32_16x16x32_bf16(aS, kfrag[ks][1], accS1, 0, 0, 0);
            accC0 = __builtin_amdgcn_mfma_f32_16x16x32_bf16(aC, kfrag[ks][0], accC0, 0, 0, 0);
            accC1 = __builtin_amdgcn_mfma_f32_16x16x32_bf16(aC, kfrag[ks][1], accC1, 0, 0, 0);
        }
        __syncthreads();   // everyone done reading s_lds/c_lds

#pragma unroll
        for (int nf = 0; nf < 2; ++nf) {
#pragma unroll
            for (int q = 0; q < 4; ++q) {
                float aS = (nf == 0) ? accS0[q] : accS1[q];
                float aC = (nf == 0) ? accC0[q] : accC1[q];
                float coup = ci[nf][q] * aS - si[nf][q] * aC;
                float tn = t[nf][q] + DT_F * (om[nf] + gk * coup);
                t[nf][q] = tn;
                float sv, cv;
                sincosf(tn, &sv, &cv);
                si[nf][q] = sv; ci[nf][q] = cv;
                const int row = hi * 4 + q;
                const int col = cb + nf * 16 + lo;
                s_lds[row][col] = f2bf_rne(sv);
                c_lds[row][col] = f2bf_rne(cv);
            }
        }
        __syncthreads();
    }

    // ---- order parameter r (f32 partials) + theta writeback -------------
#pragma unroll
    for (int q = 0; q < 4; ++q) {
        const int row = hi * 4 + q;
        rp_s[row][w * 16 + lo] = si[0][q] + si[1][q];
        rp_c[row][w * 16 + lo] = ci[0][q] + ci[1][q];
    }
#pragma unroll
    for (int nf = 0; nf < 2; ++nf) {
#pragma unroll
        for (int q = 0; q < 4; ++q) {
            const int row = hi * 4 + q;
            const int col = cb + nf * 16 + lo;
            theta[(r0 + row) * 256 + col] = atan2f(si[nf][q], ci[nf][q]);
        }
    }
    __syncthreads();

    {
        const int row = tid >> 5;
        const int i = tid & 31;
        float ssum = rp_s[row][i] + rp_s[row][i + 32] + rp_s[row][i + 64] + rp_s[row][i + 96];
        float csum = rp_c[row][i] + rp_c[row][i + 32] + rp_c[row][i + 64] + rp_c[row][i + 96];
        red_s[row][i] = ssum;
        red_c[row][i] = csum;
        __syncthreads();
#pragma unroll
        for (int off = 16; off > 0; off >>= 1) {
            if (i < off) {
                red_s[row][i] += red_s[row][i + off];
                red_c[row][i] += red_c[row][i + off];
            }
            __syncthreads();
        }
        if (i == 0) {
            float sm = red_s[row][0] * (1.0f / 256.0f);
            float cm = red_c[row][0] * (1.0f / 256.0f);
            r_out[r0 + row] = sqrtf(cm * cm + sm * sm);
        }
    }
}

// ---------------------------------------------------------------- z update (+ rmean)

__global__ __launch_bounds__(256) void z_update_kernel(const float* __restrict__ r,
                                                       float* __restrict__ scal,
                                                       const float* __restrict__ zm_p,
                                                       const float* __restrict__ zd_p) {
    __shared__ float red[256];
    int t = threadIdx.x;
    red[t] = r[t] + r[t + 256] + r[t + 512] + r[t + 768];
    __syncthreads();
#pragma unroll
    for (int off = 128; off > 0; off >>= 1) {
        if (t < off) red[t] += red[t + off];
        __syncthreads();
    }
    if (t == 0) {
        float rmean = red[0] * (1.0f / 1024.0f);
        float z = scal[SC_Z];
        float dz = (*zm_p) * (rmean - z) - (*zd_p) * (z - 0.5f);
        z = z + 0.01f * dz;
        z = fminf(fmaxf(z, 0.0f), 1.0f);
        scal[SC_Z] = z;
        scal[SC_RMEAN] = rmean;
    }
}

// ---------------------------------------------------------------- selection MLP (batched hidden mean)
// 256 blocks x 4 rows; each 256-dot split across 4 thread-groups of 64.

__global__ __launch_bounds__(256) void sel_partial_kernel(const float* __restrict__ theta,
                                                          const float* __restrict__ r,
                                                          const float* __restrict__ scal,
                                                          const float* __restrict__ W1,
                                                          const float* __restrict__ b1,
                                                          float* __restrict__ partial) {
    __shared__ float red[4][64];
    const int h = threadIdx.x & 63;
    const int part = threadIdx.x >> 6;   // 0..3 -> k-range [part*64, part*64+64)
    const int blk = blockIdx.x;
    const float z = scal[SC_Z];

    const float* wbase = W1 + part * 64 * 64 + h;
    float acc = 0.0f;

#pragma unroll
    for (int rr = 0; rr < 4; ++rr) {
        const int b = blk * 4 + rr;
        const float* th = theta + b * 256 + part * 64;
        float d0 = 0.f, d1 = 0.f, d2 = 0.f, d3 = 0.f;
#pragma unroll
        for (int kk = 0; kk < 64; kk += 4) {
            d0 = fmaf(th[kk + 0], wbase[(kk + 0) * 64], d0);
            d1 = fmaf(th[kk + 1], wbase[(kk + 1) * 64], d1);
            d2 = fmaf(th[kk + 2], wbase[(kk + 2) * 64], d2);
            d3 = fmaf(th[kk + 3], wbase[(kk + 3) * 64], d3);
        }
        red[part][h] = (d0 + d1) + (d2 + d3);
        __syncthreads();
        if (part == 0) {
            float full = red[0][h] + red[1][h] + red[2][h] + red[3][h] + b1[h]
                       + r[b] * W1[256 * 64 + h] + z * W1[257 * 64 + h];
            acc += gelu_f(full);
        }
        __syncthreads();
    }
    if (part == 0) partial[blk * 64 + h] = acc;
}

__global__ __launch_bounds__(256) void op_finalize_kernel(const float* __restrict__ partial,
                                                          const float* __restrict__ W2,
                                                          const float* __restrict__ b2,
                                                          const float* __restrict__ opstr,
                                                          const float* __restrict__ cf,
                                                          float* __restrict__ scal,
                                                          float* __restrict__ om_add) {
    __shared__ float red[4][64];
    __shared__ float hbar[64];
    __shared__ float s_sm;
    __shared__ int s_op;
    const int t = threadIdx.x;
    const int h = t & 63;
    const int q = t >> 6;   // 0..3 -> block-range [q*64, q*64+64)

    float s = 0.0f;
#pragma unroll 8
    for (int blk = q * 64; blk < q * 64 + 64; ++blk) s += partial[blk * 64 + h];
    red[q][h] = s;
    __syncthreads();
    if (t < 64) hbar[t] = (red[0][t] + red[1][t] + red[2][t] + red[3][t]) * (1.0f / 1024.0f);
    __syncthreads();
    if (t == 0) {
        float best = -1e30f;
        int op = 0;
#pragma unroll
        for (int o = 0; o < 6; ++o) {
            float l = b2[o];
            for (int hh = 0; hh < 64; ++hh) l = fmaf(hbar[hh], W2[hh * 6 + o], l);
            if (l > best) { best = l; op = o; }
        }
        float sm = opstr[op] * scal[SC_RMEAN];
        scal[SC_OP] = (float)op;
        scal[SC_OPSTR] = opstr[op];
        scal[SC_SM] = sm;
        scal[SC_KMULT] = (op == 1) ? (1.0f + sm * 0.5f)
                        : (op == 2) ? (1.0f - sm * 0.3f) : 1.0f;
        s_sm = sm;
        s_op = op;
    }
    __syncthreads();
    om_add[t] = (s_op == 5) ? cf[t] * s_sm : 0.0f;
}

// ---------------------------------------------------------------- apply operator (EXCHANGE / INHIBIT)

__global__ __launch_bounds__(256) void apply_op_kernel(float* __restrict__ theta,
                                                       const float* __restrict__ P,
                                                       const float* __restrict__ r,
                                                       const float* __restrict__ scal,
                                                       int li) {
    __shared__ float th[8][256];
    const int op = (int)scal[SC_OP];
    const int i = threadIdx.x;
    const int b0 = blockIdx.x * 8;

    if (op == 3) {
#pragma unroll
        for (int rr = 0; rr < 8; ++rr) th[rr][i] = theta[(b0 + rr) * 256 + i];
        __syncthreads();
        float acc[8] = {0.f, 0.f, 0.f, 0.f, 0.f, 0.f, 0.f, 0.f};
        for (int j = 0; j < 256; ++j) {
            float pv = P[j * 256 + i];
#pragma unroll
            for (int rr = 0; rr < 8; ++rr) acc[rr] = fmaf(th[rr][j], pv, acc[rr]);
        }
#pragma unroll
        for (int rr = 0; rr < 8; ++rr) theta[(b0 + rr) * 256 + i] = acc[rr];
    } else if (op == 4) {
        unsigned fk0, fk1;
        threefry2x32(0u, 42u, 0u, (unsigned)li, fk0, fk1);
        const float opv = scal[SC_OPSTR];
#pragma unroll
        for (int rr = 0; rr < 8; ++rr) {
            int b = b0 + rr;
            unsigned flat = (unsigned)(b * 256 + i);
            float nz = jax_normal_elem(fk0, fk1, flat);
            float strength = opv * r[b];
            theta[b * 256 + i] += nz * strength * 0.2f;
        }
    }
}

// ---------------------------------------------------------------- phase embedding

__global__ __launch_bounds__(256) void emb_kernel(const float* __restrict__ theta,
                                                  float* __restrict__ emb) {
    int idx = blockIdx.x * 256 + threadIdx.x;   // over B*256
    int b = idx >> 8, i = idx & 255;
    float t = theta[idx];
    float sv, cv;
    sincosf(t, &sv, &cv);
    emb[b * 512 + i] = cv;
    emb[b * 512 + 256 + i] = sv;
}

// ---------------------------------------------------------------- launch

extern "C" void kernel_launch(void* const* d_in, const int* in_sizes, int n_in,
                              void* d_out, int out_size, void* d_ws, size_t ws_size,
                              hipStream_t stream) {
    const float* x     = (const float*)d_in[0];
    const float* eW1   = (const float*)d_in[1];
    const float* eb1   = (const float*)d_in[2];
    const float* eW2   = (const float*)d_in[3];
    const float* eb2   = (const float*)d_in[4];
    const float* K     = (const float*)d_in[5];
    const float* omega = (const float*)d_in[6];
    const float* Kg    = (const float*)d_in[7];
    const float* opstr = (const float*)d_in[8];
    const float* exlog = (const float*)d_in[9];
    const float* cfreq = (const float*)d_in[10];
    const float* sW1   = (const float*)d_in[11];
    const float* sb1   = (const float*)d_in[12];
    const float* sW2   = (const float*)d_in[13];
    const float* sb2   = (const float*)d_in[14];
    const float* dW1   = (const float*)d_in[15];
    const float* db1   = (const float*)d_in[16];
    const float* dW2   = (const float*)d_in[17];
    const float* db2   = (const float*)d_in[18];
    const float* zm    = (const float*)d_in[19];
    const float* zd    = (const float*)d_in[20];
    float* out = (float*)d_out;

    float* ws      = (float*)d_ws;
    float* P       = ws;               // 65536
    float* theta   = P + 65536;        // 262144
    float* h       = theta + 262144;   // 524288 (enc hidden, reused as emb)
    float* dh      = h + 524288;       // 262144 (dec hidden)
    float* rbuf    = dh + 262144;      // 1024
    float* scal    = rbuf + 1024;      // 8
    float* om_add  = scal + 8;         // 256
    float* partial = om_add + 256;     // 256*64

    init_kernel<<<1, 256, 0, stream>>>(scal, om_add);

    // Sinkhorn: 5x (row-LSE, col-LSE), exp fused into last col pass
    sinkhorn_row<<<256, 256, 0, stream>>>(exlog, P);
    sinkhorn_col<false><<<256, 256, 0, stream>>>(P);
    for (int it = 1; it < 5; ++it) {
        sinkhorn_row<<<256, 256, 0, stream>>>(P, P);
        if (it < 4) sinkhorn_col<false><<<256, 256, 0, stream>>>(P);
        else        sinkhorn_col<true><<<256, 256, 0, stream>>>(P);
    }

    // encoder
    gemm_kernel<1><<<dim3(8, 16), 256, 0, stream>>>(x, eW1, eb1, h, 1024, 512, 512);
    gemm_kernel<2><<<dim3(4, 16), 256, 0, stream>>>(h, eW2, eb2, theta, 1024, 512, 256);

    // layers
    for (int li = 0; li < 4; ++li) {
        kuramoto_mfma_kernel<<<64, 512, 0, stream>>>(theta, K + li * 65536, omega + li * 256,
                                                     Kg + li, scal, om_add, rbuf);
        z_update_kernel<<<1, 256, 0, stream>>>(rbuf, scal, zm, zd);
        sel_partial_kernel<<<256, 256, 0, stream>>>(theta, rbuf, scal, sW1, sb1, partial);
        op_finalize_kernel<<<1, 256, 0, stream>>>(partial, sW2, sb2, opstr, cfreq, scal, om_add);
        apply_op_kernel<<<128, 256, 0, stream>>>(theta, P, rbuf, scal, li);
    }

    // decoder
    emb_kernel<<<1024, 256, 0, stream>>>(theta, h);
    gemm_kernel<1><<<dim3(4, 16), 256, 0, stream>>>(h, dW1, db1, dh, 1024, 512, 256);
    gemm_kernel<0><<<dim3(2, 16), 256, 0, stream>>>(dh, dW2, db2, out, 1024, 256, 128);

    (void)in_sizes; (void)n_in; (void)out_size; (void)ws_size;
}